// Round 6
// baseline (115.080 us; speedup 1.0000x reference)
//
#include <hip/hip_runtime.h>

// 3-level separable 2D DWT, bior3.5, mode='periodization'.
// out[i] = sum_j f[j] * x[(2i+1-j) mod N] along each axis.
// v6: one 32xOHT output tile per block, ONE barrier per block.
//     Row pass reads 28-float windows directly from global (L1/L2 serve the
//     halo; no s_in staging, no prefetch registers -> no spill risk).
//     lo/hi stored interleaved (float2) in one transposed LDS array with
//     pitch 2*(IR+1) dwords (== 22 mod 32): b64 writes AND b64 reads are
//     exactly 4 dwords/bank = conflict-free minimum.
//     Column pass: 4 rows/thread (OHT=32) via float2 reads, direct stores
//     (no barrier after -> stores never stall anything).

#define OW 32

template <int N, int OHT>
__global__ __launch_bounds__(256, 4) void dwt2_level(
    const float* __restrict__ src,
    float* __restrict__ aa, float* __restrict__ da,
    float* __restrict__ ad, float* __restrict__ dd)
{
    constexpr float SQ2 = 1.41421356237309504880f;
    constexpr float c_lo[12] = {
        -20.f * SQ2 / 2048.f,  60.f * SQ2 / 2048.f,   76.f * SQ2 / 2048.f,
        -388.f * SQ2 / 2048.f, -104.f * SQ2 / 2048.f, 1400.f * SQ2 / 2048.f,
        1400.f * SQ2 / 2048.f, -104.f * SQ2 / 2048.f, -388.f * SQ2 / 2048.f,
        76.f * SQ2 / 2048.f,   60.f * SQ2 / 2048.f,   -20.f * SQ2 / 2048.f };
    constexpr float c_hi4[4] = { -SQ2 / 8.f, 3.f * SQ2 / 8.f, -3.f * SQ2 / 8.f, SQ2 / 8.f };

    constexpr int h     = N >> 1;
    constexpr int mask  = N - 1;
    constexpr int IR    = 2 * OHT + 10;      // staged filter rows (74 / 42)
    constexpr int PITCH = 2 * (IR + 1);      // dwords per col strip (150 / 86), ==22 mod 32
    constexpr int NTASK = IR * 4;            // 8-col row-pass tasks (296 / 168)
    constexpr int RPT   = OHT * OW / 256;    // output rows per thread in col pass (4 / 2)
    constexpr int E     = 2 * RPT + 10;      // staged rows read per thread (18 / 14)

    const int bc  = blockIdx.z;
    const int j0  = blockIdx.x * OW;
    const int i0  = blockIdx.y * OHT;
    const int tid = threadIdx.x;

    __shared__ float s_T[OW * PITCH];        // interleaved {lo,hi} transposed

    const float* img = src + (unsigned)bc * (unsigned)(N * N);
    const int c0 = 2 * j0 - 12;              // multiple of 4
    const int r0 = 2 * i0 - 10;

    // ---- Phase 1: row pass straight from global. Task = (row r, 8-col group m).
    for (int t = tid; t < NTASK; t += 256) {
        const int r  = t >> 2;
        const int m  = t & 3;
        const int gr = (r0 + r) & mask;
        const float* row = img + (unsigned)(gr * N);
        const int cb = c0 + 16 * m;          // window [cb, cb+27], 16B aligned
        float v[28];
        if (cb >= 0) {
            #pragma unroll
            for (int q = 0; q < 7; ++q)
                *(float4*)&v[4 * q] = *(const float4*)&row[cb + 4 * q];
        } else {                              // left-edge wrap (blockIdx.x==0, m==0)
            #pragma unroll
            for (int k = 0; k < 28; ++k)
                v[k] = row[(cb + k) & mask];
        }
        #pragma unroll
        for (int d = 0; d < 8; ++d) {
            float lo = 0.f, hi = 0.f;
            #pragma unroll
            for (int jc = 0; jc < 12; ++jc)
                lo += c_lo[jc] * v[2 * d + 13 - jc];
            #pragma unroll
            for (int k = 0; k < 4; ++k)
                hi += c_hi4[k] * v[2 * d + 9 - k];
            *(float2*)&s_T[(8 * m + d) * PITCH + 2 * r] = make_float2(lo, hi);
        }
    }
    __syncthreads();                          // the only barrier

    // ---- Phase 2: column pass. Thread (tx, g) -> col j0+tx, rows RPT*g..RPT*g+RPT-1.
    const int tx = tid & 31;
    const int g  = tid >> 5;                  // 0..7
    float l[E], hh[E];
    #pragma unroll
    for (int e = 0; e < E; ++e) {
        float2 p = *(const float2*)&s_T[tx * PITCH + 2 * (2 * RPT * g + e)];
        l[e]  = p.x;
        hh[e] = p.y;
    }
    #pragma unroll
    for (int u = 0; u < RPT; ++u) {
        float vaa = 0.f, vad = 0.f;
        #pragma unroll
        for (int jr = 0; jr < 12; ++jr) {
            vaa += c_lo[jr] * l[2 * u + 11 - jr];
            vad += c_lo[jr] * hh[2 * u + 11 - jr];
        }
        float vda = 0.f, vdd = 0.f;
        #pragma unroll
        for (int k = 0; k < 4; ++k) {
            vda += c_hi4[k] * l[2 * u + 7 - k];
            vdd += c_hi4[k] * hh[2 * u + 7 - k];
        }
        const int orow = i0 + RPT * g + u;
        const unsigned ob = (unsigned)((bc * h + orow) * h + j0 + tx);
        aa[ob] = vaa;
        da[ob] = vda;
        ad[ob] = vad;
        dd[ob] = vdd;
    }
}

extern "C" void kernel_launch(void* const* d_in, const int* in_sizes, int n_in,
                              void* d_out, int out_size, void* d_ws, size_t ws_size,
                              hipStream_t stream) {
    const float* x = (const float*)d_in[0];
    float* out = (float*)d_out;
    float* ws  = (float*)d_ws;

    // 24 independent N x N images (8 batch x 3 channels).
    const size_t s512 = (size_t)24 * 512 * 512;
    const size_t s256 = (size_t)24 * 256 * 256;
    const size_t s128 = (size_t)24 * 128 * 128;

    // d_out layout (return order): a | h3(da,ad,dd) | h2(...) | h1(...)
    float* a_out = out;
    float* h3 = out + s128;
    float* h2 = out + 4 * s128;
    float* h1 = out + 4 * s128 + 3 * s256;

    float* aa1 = ws;          // 512^2 intermediate
    float* aa2 = ws + s512;   // 256^2 intermediate
    (void)in_sizes; (void)n_in; (void)out_size; (void)ws_size;

    dim3 blk(256, 1, 1);
    // level 1: 1024 -> 512   (16 x 16 x 24 = 6144 blocks)
    dwt2_level<1024, 32><<<dim3(512 / OW, 512 / 32, 24), blk, 0, stream>>>(
        x, aa1, h1, h1 + s512, h1 + 2 * s512);
    // level 2: 512 -> 256    (8 x 16 x 24 = 3072 blocks)
    dwt2_level<512, 16><<<dim3(256 / OW, 256 / 16, 24), blk, 0, stream>>>(
        aa1, aa2, h2, h2 + s256, h2 + 2 * s256);
    // level 3: 256 -> 128    (4 x 8 x 24 = 768 blocks)
    dwt2_level<256, 16><<<dim3(128 / OW, 128 / 16, 24), blk, 0, stream>>>(
        aa2, a_out, h3, h3 + s128, h3 + 2 * s128);
}

// Round 7
// 77.160 us; speedup vs baseline: 1.4914x; 1.4914x over previous
//
#include <hip/hip_runtime.h>

// 3-level separable 2D DWT, bior3.5, mode='periodization'.
// out[i] = sum_j f[j] * x[(2i+1-j) mod N] along each axis.
// v7: v4 pipeline + REAL async prefetch:
//     - raw s_barrier with lgkmcnt(0)-only (no vmcnt drain -> prefetch loads
//       stay in flight across both compute phases; rule-18 sched_barrier fence)
//     - sched_barrier(0) after load issue so the compiler can't sink them
//     - interleaved {lo,hi} float2 transposed LDS (PITCH=86: conflict-free,
//       8B-aligned b64 writes AND reads; v6-verified layout)
//     - launch_bounds(256,5): VGPR cap 102, no spill (v5 lesson)

#define OW 32                  // output cols per block
#define OHS 16                 // output rows per step
#define IN_ROWS 42             // 2*OHS + 10 staged input rows per step
#define QPR 20                 // float4 quads per staged row (80 cols)
#define NQ 840                 // staged quads per step (IN_ROWS*QPR)
#define SPITCH 84              // s_in dword pitch (uniform-bank b128 reads)
#define PITCH 86               // interleaved transposed pitch (22 mod 32)

// Barrier with LDS-only drain: prefetch vmem loads stay outstanding.
#define BAR() do { \
    asm volatile("s_waitcnt lgkmcnt(0)" ::: "memory"); \
    __builtin_amdgcn_s_barrier(); \
    __builtin_amdgcn_sched_barrier(0); \
  } while (0)

template <int N, int NSTEP>
__global__ __launch_bounds__(256, 5) void dwt2_level(
    const float* __restrict__ src,
    float* __restrict__ aa, float* __restrict__ da,
    float* __restrict__ ad, float* __restrict__ dd)
{
    constexpr float SQ2 = 1.41421356237309504880f;
    constexpr float c_lo[12] = {
        -20.f * SQ2 / 2048.f,  60.f * SQ2 / 2048.f,   76.f * SQ2 / 2048.f,
        -388.f * SQ2 / 2048.f, -104.f * SQ2 / 2048.f, 1400.f * SQ2 / 2048.f,
        1400.f * SQ2 / 2048.f, -104.f * SQ2 / 2048.f, -388.f * SQ2 / 2048.f,
        76.f * SQ2 / 2048.f,   60.f * SQ2 / 2048.f,   -20.f * SQ2 / 2048.f };
    constexpr float c_hi4[4] = { -SQ2 / 8.f, 3.f * SQ2 / 8.f, -3.f * SQ2 / 8.f, SQ2 / 8.f };

    constexpr int h    = N >> 1;
    constexpr int mask = N - 1;

    const int bc  = blockIdx.z;
    const int j0  = blockIdx.x * OW;
    const int i0  = blockIdx.y * (OHS * NSTEP);
    const int tid = threadIdx.x;

    __shared__ float s_in[IN_ROWS * SPITCH];   // 14.1 KB
    __shared__ float s_T[OW * PITCH];          // 11.0 KB  (25.1 KB -> 6 blocks/CU)

    const float* img = src + (unsigned)bc * (unsigned)(N * N);
    const int c0 = 2 * j0 - 12;   // quad-aligned col base (multiple of 4)

    // Staged quad q: contiguous, 16B-aligned global read (wrap keeps alignment).
    auto ldq = [&](int s, int q) -> float4 {
        const int r  = q / QPR;
        const int c4 = q - r * QPR;
        const int gr = (2 * (i0 + OHS * s) - 10 + r) & mask;
        const int gc = (c0 + 4 * c4) & mask;
        return *(const float4*)(img + (unsigned)(gr * N + gc));
    };
    auto stq = [&](int q, float4 v) {
        const int r  = q / QPR;
        const int c4 = q - r * QPR;
        *(float4*)&s_in[r * SPITCH + 4 * c4] = v;
    };

    const bool has4 = tid < (NQ - 768);   // 72 threads stage a 4th quad

    // ---- prologue: stage step 0 ----
    float4 pf0 = ldq(0, tid);
    float4 pf1 = ldq(0, tid + 256);
    float4 pf2 = ldq(0, tid + 512);
    float4 pf3 = make_float4(0.f, 0.f, 0.f, 0.f);
    if (has4) pf3 = ldq(0, tid + 768);
    stq(tid, pf0);
    stq(tid + 256, pf1);
    stq(tid + 512, pf2);
    if (has4) stq(tid + 768, pf3);
    BAR();

    for (int s = 0; s < NSTEP; ++s) {
        // issue next step's loads NOW; with lgkm-only barriers they remain
        // outstanding across phase 1 + mid barrier + phase 2.
        if (s + 1 < NSTEP) {
            pf0 = ldq(s + 1, tid);
            pf1 = ldq(s + 1, tid + 256);
            pf2 = ldq(s + 1, tid + 512);
            if (has4) pf3 = ldq(s + 1, tid + 768);
        }
        __builtin_amdgcn_sched_barrier(0);   // pin the issue point

        // ---- phase 1: row pass (threads 0..167), 8 output cols per task ----
        if (tid < IN_ROWS * 4) {
            const int m = tid & 3;
            const int r = tid >> 2;
            const float* p = &s_in[r * SPITCH + 16 * m];
            float v[28];
            #pragma unroll
            for (int q = 0; q < 7; ++q)
                *(float4*)&v[4 * q] = *(const float4*)&p[4 * q];
            #pragma unroll
            for (int d = 0; d < 8; ++d) {
                float lo = 0.f, hi = 0.f;
                #pragma unroll
                for (int jc = 0; jc < 12; ++jc)
                    lo += c_lo[jc] * v[2 * d + 13 - jc];
                #pragma unroll
                for (int k = 0; k < 4; ++k)
                    hi += c_hi4[k] * v[2 * d + 9 - k];
                *(float2*)&s_T[(8 * m + d) * PITCH + 2 * r] = make_float2(lo, hi);
            }
        }
        BAR();                                // mid: LDS visible, loads still in flight

        // ---- phase 2: column pass. thread (tx,ty) -> col j0+tx, rows 2ty, 2ty+1 ----
        {
            const int tx = tid & 31;
            const int ty = tid >> 5;          // 0..7
            float l[14], hh[14];
            #pragma unroll
            for (int e = 0; e < 14; ++e) {
                float2 p = *(const float2*)&s_T[tx * PITCH + 2 * (4 * ty + e)];
                l[e]  = p.x;
                hh[e] = p.y;
            }
            float vaa0 = 0.f, vaa1 = 0.f, vad0 = 0.f, vad1 = 0.f;
            #pragma unroll
            for (int jr = 0; jr < 12; ++jr) {
                vaa0 += c_lo[jr] * l[11 - jr];
                vaa1 += c_lo[jr] * l[13 - jr];
                vad0 += c_lo[jr] * hh[11 - jr];
                vad1 += c_lo[jr] * hh[13 - jr];
            }
            float vda0 = 0.f, vda1 = 0.f, vdd0 = 0.f, vdd1 = 0.f;
            #pragma unroll
            for (int k = 0; k < 4; ++k) {
                vda0 += c_hi4[k] * l[7 - k];
                vda1 += c_hi4[k] * l[9 - k];
                vdd0 += c_hi4[k] * hh[7 - k];
                vdd1 += c_hi4[k] * hh[9 - k];
            }
            const int orow = i0 + OHS * s + 2 * ty;
            const unsigned ob = (unsigned)((bc * h + orow) * h + j0 + tx);
            aa[ob] = vaa0;  aa[ob + h] = vaa1;
            da[ob] = vda0;  da[ob + h] = vda1;
            ad[ob] = vad0;  ad[ob + h] = vad1;
            dd[ob] = vdd0;  dd[ob + h] = vdd1;
        }

        // ---- write prefetched quads into s_in for step s+1 ----
        // (compiler inserts the per-wave vmcnt wait for pf* here)
        if (s + 1 < NSTEP) {
            stq(tid, pf0);
            stq(tid + 256, pf1);
            stq(tid + 512, pf2);
            if (has4) stq(tid + 768, pf3);
        }
        BAR();                                // end: s_in(step s+1) visible
    }
}

extern "C" void kernel_launch(void* const* d_in, const int* in_sizes, int n_in,
                              void* d_out, int out_size, void* d_ws, size_t ws_size,
                              hipStream_t stream) {
    const float* x = (const float*)d_in[0];
    float* out = (float*)d_out;
    float* ws  = (float*)d_ws;

    // 24 independent N x N images (8 batch x 3 channels).
    const size_t s512 = (size_t)24 * 512 * 512;
    const size_t s256 = (size_t)24 * 256 * 256;
    const size_t s128 = (size_t)24 * 128 * 128;

    // d_out layout (return order): a | h3(da,ad,dd) | h2(...) | h1(...)
    float* a_out = out;
    float* h3 = out + s128;
    float* h2 = out + 4 * s128;
    float* h1 = out + 4 * s128 + 3 * s256;

    float* aa1 = ws;          // 512^2 intermediate
    float* aa2 = ws + s512;   // 256^2 intermediate
    (void)in_sizes; (void)n_in; (void)out_size; (void)ws_size;

    dim3 blk(256, 1, 1);
    // level 1: 1024 -> 512   (16 x 8 x 24 = 3072 blocks, NSTEP=4)
    dwt2_level<1024, 4><<<dim3(16, 8, 24), blk, 0, stream>>>(
        x, aa1, h1, h1 + s512, h1 + 2 * s512);
    // level 2: 512 -> 256    (8 x 8 x 24 = 1536 blocks, NSTEP=2)
    dwt2_level<512, 2><<<dim3(8, 8, 24), blk, 0, stream>>>(
        aa1, aa2, h2, h2 + s256, h2 + 2 * s256);
    // level 3: 256 -> 128    (4 x 8 x 24 = 768 blocks, NSTEP=1)
    dwt2_level<256, 1><<<dim3(4, 8, 24), blk, 0, stream>>>(
        aa2, a_out, h3, h3 + s128, h3 + 2 * s128);
}